// Round 4
// baseline (260.924 us; speedup 1.0000x reference)
//
#include <hip/hip_runtime.h>

#define ROWS  16
#define BLOCK 512
#define PAD   620   // 616 padded; 2480B row = 16B-aligned, de-aliases LDS banks

typedef float f4v __attribute__((ext_vector_type(4)));  // native vec for nontemporal builtin

__global__ __launch_bounds__(BLOCK, 6) void spe_fused(
    const float* __restrict__ nodef,   // [200000,172]
    const float* __restrict__ edgef,   // [500000,172]
    const int*   __restrict__ src_ids, // [8192]
    const int*   __restrict__ dst_ids, // [8192]
    const float* __restrict__ itimes,  // [8192]
    const int*   __restrict__ s_nbr,   // [8192,32]
    const int*   __restrict__ s_eid,   // [8192,32]
    const float* __restrict__ s_t,     // [8192,32]
    const int*   __restrict__ d_nbr,
    const int*   __restrict__ d_eid,
    const float* __restrict__ d_t,
    const float* __restrict__ tw,      // [100]
    const float* __restrict__ tb,      // [100]
    const float* __restrict__ W,       // [616,172]
    const float* __restrict__ bout,    // [172]
    float*       __restrict__ out)     // [3,8192,172]
{
    __shared__ float inp[ROWS * PAD];     // per-row 616-dim input vector
    __shared__ int   noff[ROWS * 32];     // nbr_id * 172
    __shared__ int   eoff[ROWS * 32];     // edge_id * 172
    __shared__ float dtm[ROWS * 32];      // interact_time - nbr_time
    __shared__ float msk[ROWS * 32];      // 0 if nbr_id==0 else 1
    __shared__ int   curoff[ROWS];        // node_id * 172
    __shared__ float twl[100], tbl[100];

    const int tid     = threadIdx.x;
    const int side    = blockIdx.x >> 9;           // 512 blocks per side
    const int rowbase = (blockIdx.x & 511) * ROWS;

    const int*   nbr  = side ? d_nbr : s_nbr;
    const int*   eidp = side ? d_eid : s_eid;
    const float* ntp  = side ? d_t   : s_t;
    const int*   nids = side ? dst_ids : src_ids;

    // ---- stage ids / dt / mask (exactly one item per thread) ----
    {
        int i   = tid;                    // ROWS*32 == 512 == BLOCK
        int g   = rowbase * 32 + i;
        int nid = nbr[g];
        noff[i] = nid * 172;
        eoff[i] = eidp[g] * 172;
        dtm[i]  = itimes[rowbase + (i >> 5)] - ntp[g];
        msk[i]  = (nid == 0) ? 0.f : 1.f;
    }
    if (tid < ROWS) curoff[tid] = nids[rowbase + tid] * 172;
    if (tid < 100) { twl[tid] = tw[tid]; tbl[tid] = tb[tid]; }
    __syncthreads();

    // ---- cur node copy (float4): inp[r][0:172] ----
    for (int i = tid; i < ROWS * 43; i += BLOCK) {
        int r = i / 43, c = i - r * 43;
        *(float4*)&inp[r * PAD + 4 * c] =
            *(const float4*)&nodef[curoff[r] + 4 * c];
    }

    // ---- node gather mean (float4, 16 loads in flight): inp[r][172+d] ----
    for (int i = tid; i < ROWS * 43; i += BLOCK) {
        int r = i / 43, c = i - r * 43;
        const int dd = 4 * c, rb = r * 32;
        float4 acc = {0.f, 0.f, 0.f, 0.f};
        #pragma unroll
        for (int s0 = 0; s0 < 32; s0 += 16) {
            float4 v[16];
            #pragma unroll
            for (int u = 0; u < 16; ++u)
                v[u] = *(const float4*)&nodef[noff[rb + s0 + u] + dd];
            #pragma unroll
            for (int u = 0; u < 16; ++u) {
                acc.x += v[u].x; acc.y += v[u].y;
                acc.z += v[u].z; acc.w += v[u].w;
            }
        }
        acc.x *= (1.f/32.f); acc.y *= (1.f/32.f);
        acc.z *= (1.f/32.f); acc.w *= (1.f/32.f);
        *(float4*)&inp[r * PAD + 172 + dd] = acc;
    }

    // ---- edge gather mean (float4 nontemporal, 16 in flight): inp[r][344+d] ----
    for (int i = tid; i < ROWS * 43; i += BLOCK) {
        int r = i / 43, c = i - r * 43;
        const int dd = 4 * c, rb = r * 32;
        float4 acc = {0.f, 0.f, 0.f, 0.f};
        #pragma unroll
        for (int s0 = 0; s0 < 32; s0 += 16) {
            f4v v[16];
            #pragma unroll
            for (int u = 0; u < 16; ++u)
                v[u] = __builtin_nontemporal_load(
                    (const f4v*)&edgef[eoff[rb + s0 + u] + dd]);
            #pragma unroll
            for (int u = 0; u < 16; ++u) {
                acc.x += v[u].x; acc.y += v[u].y;
                acc.z += v[u].z; acc.w += v[u].w;
            }
        }
        acc.x *= (1.f/32.f); acc.y *= (1.f/32.f);
        acc.z *= (1.f/32.f); acc.w *= (1.f/32.f);
        *(float4*)&inp[r * PAD + 344 + dd] = acc;
    }

    // ---- time encoding: inp[r][516+j] ----
    for (int i = tid; i < ROWS * 100; i += BLOCK) {
        int r = i / 100, j = i - r * 100;
        const int rb = r * 32;
        float w = twl[j], b = tbl[j];
        float acc = 0.f;
        #pragma unroll
        for (int s = 0; s < 32; ++s)
            acc += msk[rb + s] * __cosf(dtm[rb + s] * w + b);
        inp[r * PAD + 516 + j] = acc * (1.f / 32.f);
    }
    __syncthreads();

    // ---- GEMM: out[16,172] = relu(inp[16,616] @ W[616,172] + b) ----
    // 344 threads = 8 row-tiles x 43 col-tiles, each thread 2 rows x 4 cols
    if (tid < 344) {
        const int ct = tid % 43, rt = tid / 43;
        const int j0 = ct * 4, r0 = rt * 2;
        float acc[2][4] = {};
        float a[2][4];
        for (int k = 0; k < 616; k += 4) {
            #pragma unroll
            for (int ri = 0; ri < 2; ++ri)
                *(float4*)&a[ri][0] = *(const float4*)&inp[(r0 + ri) * PAD + k];
            #pragma unroll
            for (int kk = 0; kk < 4; ++kk) {
                float4 wv = *(const float4*)&W[(k + kk) * 172 + j0];
                #pragma unroll
                for (int ri = 0; ri < 2; ++ri) {
                    acc[ri][0] += a[ri][kk] * wv.x;
                    acc[ri][1] += a[ri][kk] * wv.y;
                    acc[ri][2] += a[ri][kk] * wv.z;
                    acc[ri][3] += a[ri][kk] * wv.w;
                }
            }
        }
        float4 bias = *(const float4*)&bout[j0];
        #pragma unroll
        for (int ri = 0; ri < 2; ++ri) {
            int row = rowbase + r0 + ri;
            float4 v;
            v.x = fmaxf(acc[ri][0] + bias.x, 0.f);
            v.y = fmaxf(acc[ri][1] + bias.y, 0.f);
            v.z = fmaxf(acc[ri][2] + bias.z, 0.f);
            v.w = fmaxf(acc[ri][3] + bias.w, 0.f);
            *(float4*)&out[(size_t)(side * 8192 + row) * 172 + j0] = v;
        }
    }

    // ---- dummy third output = zeros (written by side-0 blocks, float4) ----
    if (side == 0) {
        const float4 z = {0.f, 0.f, 0.f, 0.f};
        for (int i = tid; i < ROWS * 43; i += BLOCK) {
            int r = i / 43, c = i - r * 43;
            *(float4*)&out[(size_t)(2 * 8192 + rowbase + r) * 172 + 4 * c] = z;
        }
    }
}

extern "C" void kernel_launch(void* const* d_in, const int* in_sizes, int n_in,
                              void* d_out, int out_size, void* d_ws, size_t ws_size,
                              hipStream_t stream) {
    const float* nodef   = (const float*)d_in[0];
    const float* edgef   = (const float*)d_in[1];
    const int*   src_ids = (const int*)  d_in[2];
    const int*   dst_ids = (const int*)  d_in[3];
    const float* itimes  = (const float*)d_in[4];
    const int*   s_nbr   = (const int*)  d_in[5];
    const int*   s_eid   = (const int*)  d_in[6];
    const float* s_t     = (const float*)d_in[7];
    const int*   d_nbr   = (const int*)  d_in[8];
    const int*   d_eid   = (const int*)  d_in[9];
    const float* d_t     = (const float*)d_in[10];
    const float* tw      = (const float*)d_in[11];
    const float* tb      = (const float*)d_in[12];
    const float* W       = (const float*)d_in[13];
    const float* bout    = (const float*)d_in[14];
    float* out = (float*)d_out;

    spe_fused<<<1024, BLOCK, 0, stream>>>(
        nodef, edgef, src_ids, dst_ids, itimes,
        s_nbr, s_eid, s_t, d_nbr, d_eid, d_t,
        tw, tb, W, bout, out);
}

// Round 5
// 221.690 us; speedup vs baseline: 1.1770x; 1.1770x over previous
//
#include <hip/hip_runtime.h>

#define ROWS  16
#define BLOCK 512
#define PAD   620   // 616 padded; 2480B row = 16B-aligned, de-aliases LDS banks

__global__ __launch_bounds__(BLOCK) void spe_fused(
    const float* __restrict__ nodef,   // [200000,172]
    const float* __restrict__ edgef,   // [500000,172]
    const int*   __restrict__ src_ids, // [8192]
    const int*   __restrict__ dst_ids, // [8192]
    const float* __restrict__ itimes,  // [8192]
    const int*   __restrict__ s_nbr,   // [8192,32]
    const int*   __restrict__ s_eid,   // [8192,32]
    const float* __restrict__ s_t,     // [8192,32]
    const int*   __restrict__ d_nbr,
    const int*   __restrict__ d_eid,
    const float* __restrict__ d_t,
    const float* __restrict__ tw,      // [100]
    const float* __restrict__ tb,      // [100]
    const float* __restrict__ W,       // [616,172]
    const float* __restrict__ bout,    // [172]
    float*       __restrict__ out)     // [3,8192,172]
{
    __shared__ float inp[ROWS * PAD];     // per-row 616-dim input vector
    __shared__ int   noff[ROWS * 32];     // nbr_id * 172
    __shared__ int   eoff[ROWS * 32];     // edge_id * 172
    __shared__ float dtm[ROWS * 32];      // interact_time - nbr_time
    __shared__ float msk[ROWS * 32];      // 0 if nbr_id==0 else 1
    __shared__ int   curoff[ROWS];        // node_id * 172
    __shared__ float twl[100], tbl[100];

    const int tid     = threadIdx.x;
    const int side    = blockIdx.x >> 9;           // 512 blocks per side
    const int rowbase = (blockIdx.x & 511) * ROWS;

    const int*   nbr  = side ? d_nbr : s_nbr;
    const int*   eidp = side ? d_eid : s_eid;
    const float* ntp  = side ? d_t   : s_t;
    const int*   nids = side ? dst_ids : src_ids;

    // ---- stage ids / dt / mask (exactly one item per thread) ----
    {
        int i   = tid;                    // ROWS*32 == 512 == BLOCK
        int g   = rowbase * 32 + i;
        int nid = nbr[g];
        noff[i] = nid * 172;
        eoff[i] = eidp[g] * 172;
        dtm[i]  = itimes[rowbase + (i >> 5)] - ntp[g];
        msk[i]  = (nid == 0) ? 0.f : 1.f;
    }
    if (tid < ROWS) curoff[tid] = nids[rowbase + tid] * 172;
    if (tid < 100) { twl[tid] = tw[tid]; tbl[tid] = tb[tid]; }
    __syncthreads();

    // ---- cur node copy (float4): inp[r][0:172] ----
    for (int i = tid; i < ROWS * 43; i += BLOCK) {
        int r = i / 43, c = i - r * 43;
        *(float4*)&inp[r * PAD + 4 * c] =
            *(const float4*)&nodef[curoff[r] + 4 * c];
    }

    // ---- node gather mean (float4, 8 loads in flight): inp[r][172+d] ----
    for (int i = tid; i < ROWS * 43; i += BLOCK) {
        int r = i / 43, c = i - r * 43;
        const int dd = 4 * c, rb = r * 32;
        float4 acc = {0.f, 0.f, 0.f, 0.f};
        #pragma unroll
        for (int s0 = 0; s0 < 32; s0 += 8) {
            float4 v[8];
            #pragma unroll
            for (int u = 0; u < 8; ++u)
                v[u] = *(const float4*)&nodef[noff[rb + s0 + u] + dd];
            #pragma unroll
            for (int u = 0; u < 8; ++u) {
                acc.x += v[u].x; acc.y += v[u].y;
                acc.z += v[u].z; acc.w += v[u].w;
            }
        }
        acc.x *= (1.f/32.f); acc.y *= (1.f/32.f);
        acc.z *= (1.f/32.f); acc.w *= (1.f/32.f);
        *(float4*)&inp[r * PAD + 172 + dd] = acc;
    }

    // ---- edge gather mean (float4, 8 loads in flight): inp[r][344+d] ----
    for (int i = tid; i < ROWS * 43; i += BLOCK) {
        int r = i / 43, c = i - r * 43;
        const int dd = 4 * c, rb = r * 32;
        float4 acc = {0.f, 0.f, 0.f, 0.f};
        #pragma unroll
        for (int s0 = 0; s0 < 32; s0 += 8) {
            float4 v[8];
            #pragma unroll
            for (int u = 0; u < 8; ++u)
                v[u] = *(const float4*)&edgef[eoff[rb + s0 + u] + dd];
            #pragma unroll
            for (int u = 0; u < 8; ++u) {
                acc.x += v[u].x; acc.y += v[u].y;
                acc.z += v[u].z; acc.w += v[u].w;
            }
        }
        acc.x *= (1.f/32.f); acc.y *= (1.f/32.f);
        acc.z *= (1.f/32.f); acc.w *= (1.f/32.f);
        *(float4*)&inp[r * PAD + 344 + dd] = acc;
    }

    // ---- time encoding: inp[r][516+j] ----
    for (int i = tid; i < ROWS * 100; i += BLOCK) {
        int r = i / 100, j = i - r * 100;
        const int rb = r * 32;
        float w = twl[j], b = tbl[j];
        float acc = 0.f;
        #pragma unroll
        for (int s = 0; s < 32; ++s)
            acc += msk[rb + s] * __cosf(dtm[rb + s] * w + b);
        inp[r * PAD + 516 + j] = acc * (1.f / 32.f);
    }
    __syncthreads();

    // ---- GEMM: out[16,172] = relu(inp[16,616] @ W[616,172] + b) ----
    // 344 threads = 8 row-tiles x 43 col-tiles, each thread 2 rows x 4 cols
    if (tid < 344) {
        const int ct = tid % 43, rt = tid / 43;
        const int j0 = ct * 4, r0 = rt * 2;
        float acc[2][4] = {};
        float a[2][4];
        for (int k = 0; k < 616; k += 4) {
            #pragma unroll
            for (int ri = 0; ri < 2; ++ri)
                *(float4*)&a[ri][0] = *(const float4*)&inp[(r0 + ri) * PAD + k];
            #pragma unroll
            for (int kk = 0; kk < 4; ++kk) {
                float4 wv = *(const float4*)&W[(k + kk) * 172 + j0];
                #pragma unroll
                for (int ri = 0; ri < 2; ++ri) {
                    acc[ri][0] += a[ri][kk] * wv.x;
                    acc[ri][1] += a[ri][kk] * wv.y;
                    acc[ri][2] += a[ri][kk] * wv.z;
                    acc[ri][3] += a[ri][kk] * wv.w;
                }
            }
        }
        float4 bias = *(const float4*)&bout[j0];
        #pragma unroll
        for (int ri = 0; ri < 2; ++ri) {
            int row = rowbase + r0 + ri;
            float4 v;
            v.x = fmaxf(acc[ri][0] + bias.x, 0.f);
            v.y = fmaxf(acc[ri][1] + bias.y, 0.f);
            v.z = fmaxf(acc[ri][2] + bias.z, 0.f);
            v.w = fmaxf(acc[ri][3] + bias.w, 0.f);
            *(float4*)&out[(size_t)(side * 8192 + row) * 172 + j0] = v;
        }
    }

    // ---- dummy third output = zeros (written by side-0 blocks, float4) ----
    if (side == 0) {
        const float4 z = {0.f, 0.f, 0.f, 0.f};
        for (int i = tid; i < ROWS * 43; i += BLOCK) {
            int r = i / 43, c = i - r * 43;
            *(float4*)&out[(size_t)(2 * 8192 + rowbase + r) * 172 + 4 * c] = z;
        }
    }
}

extern "C" void kernel_launch(void* const* d_in, const int* in_sizes, int n_in,
                              void* d_out, int out_size, void* d_ws, size_t ws_size,
                              hipStream_t stream) {
    const float* nodef   = (const float*)d_in[0];
    const float* edgef   = (const float*)d_in[1];
    const int*   src_ids = (const int*)  d_in[2];
    const int*   dst_ids = (const int*)  d_in[3];
    const float* itimes  = (const float*)d_in[4];
    const int*   s_nbr   = (const int*)  d_in[5];
    const int*   s_eid   = (const int*)  d_in[6];
    const float* s_t     = (const float*)d_in[7];
    const int*   d_nbr   = (const int*)  d_in[8];
    const int*   d_eid   = (const int*)  d_in[9];
    const float* d_t     = (const float*)d_in[10];
    const float* tw      = (const float*)d_in[11];
    const float* tb      = (const float*)d_in[12];
    const float* W       = (const float*)d_in[13];
    const float* bout    = (const float*)d_in[14];
    float* out = (float*)d_out;

    spe_fused<<<1024, BLOCK, 0, stream>>>(
        nodef, edgef, src_ids, dst_ids, itimes,
        s_nbr, s_eid, s_t, d_nbr, d_eid, d_t,
        tw, tb, W, bout, out);
}